// Round 3
// baseline (199.531 us; speedup 1.0000x reference)
//
#include <hip/hip_runtime.h>
#include <hip/hip_bf16.h>

// out[b,d1,d2] = (x[b,d1,d2,3] > 0.5f) ? (float)d1 : 0.0f
// x: [8, 1024, 1024, 4] fp32 contiguous. out: [8, 1024, 1024] fp32.
// Memory-bound: 134 MB read + 33.5 MB write -> ~24-27 us floor at 6.3-6.9 TB/s.
//
// Each lane owns 4 consecutive output elements = one 64 B input cacheline.
// Only the 4 'w' channels (offsets +12,+28,+44,+60) are loaded into VGPRs;
// the HBM line is fetched once either way, but L1->VGPR traffic drops 4x vs
// loading full float4s, and the store is a coalesced 16 B/lane vector store.
// Native ext_vector_type (not HIP float4) so nontemporal builtins accept it.

typedef float f32x4 __attribute__((ext_vector_type(4)));

__global__ __launch_bounds__(256) void Model_58609123721280_kernel(
    const float* __restrict__ x,
    f32x4* __restrict__ out,
    int nq)                         // quads = B*D1*D2/4
{
    int i = blockIdx.x * blockDim.x + threadIdx.x;
    if (i >= nq) return;
    const float* p = x + (size_t)i * 16;   // 4 elems x 4 channels
    float w0 = __builtin_nontemporal_load(p + 3);
    float w1 = __builtin_nontemporal_load(p + 7);
    float w2 = __builtin_nontemporal_load(p + 11);
    float w3 = __builtin_nontemporal_load(p + 15);
    // elem index e = 4i+k, all 4 share d1 = (e>>10)&1023 = (i>>8)&1023
    float d1 = (float)((i >> 8) & 1023);
    f32x4 o;
    o.x = (w0 > 0.5f) ? d1 : 0.0f;
    o.y = (w1 > 0.5f) ? d1 : 0.0f;
    o.z = (w2 > 0.5f) ? d1 : 0.0f;
    o.w = (w3 > 0.5f) ? d1 : 0.0f;
    __builtin_nontemporal_store(o, out + i);
}

extern "C" void kernel_launch(void* const* d_in, const int* in_sizes, int n_in,
                              void* d_out, int out_size, void* d_ws, size_t ws_size,
                              hipStream_t stream) {
    const float* x = (const float*)d_in[0];
    f32x4* out = (f32x4*)d_out;
    int nq = out_size / 4;                   // 2,097,152 quads
    int block = 256;
    int grid = (nq + block - 1) / block;     // 8192 blocks
    Model_58609123721280_kernel<<<grid, block, 0, stream>>>(x, out, nq);
}